// Round 12
// baseline (236.751 us; speedup 1.0000x reference)
//
#include <hip/hip_runtime.h>
#include <hip/hip_bf16.h>
#include <math.h>

typedef __hip_bfloat16 bf16;
typedef __attribute__((ext_vector_type(8))) short frag8;
typedef __attribute__((ext_vector_type(4))) float f32x4;

#define HW  1296
#define CH  128
#define TT  1327104   // 8 * 1296 * 128

__device__ __forceinline__ float b2f(bf16 v) { return __bfloat162float(v); }
__device__ __forceinline__ float bits2f(unsigned short u) {
    return __uint_as_float(((unsigned)u) << 16);
}
__device__ __forceinline__ short f2bs(float f) {
    bf16 h = __float2bfloat16(f);
    return *reinterpret_cast<short*>(&h);
}
__device__ __forceinline__ float frcp(float x) { return __builtin_amdgcn_rcpf(x); }
__device__ __forceinline__ float fsigm(float x) { return frcp(1.0f + __expf(-x)); }
__device__ __forceinline__ float ftanh(float x) {
    float xc = fminf(15.0f, fmaxf(-15.0f, x));
    float e = __expf(2.0f * xc);
    return (e - 1.0f) * frcp(e + 1.0f);
}
// round-half-up f32->bf16 pair pack: 2 adds + 1 v_perm (vs ~14 VALU for 2x RNE f2bs)
__device__ __forceinline__ int packrh(float a, float b) {
    unsigned ua = __float_as_uint(a) + 0x8000u;
    unsigned ub = __float_as_uint(b) + 0x8000u;
    return (int)__builtin_amdgcn_perm(ub, ua, 0x07060302);
}
__device__ __forceinline__ int2 pack4(float a, float b, float c, float d) {
    int2 r; r.x = packrh(a, b); r.y = packrh(c, d); return r;
}

// inline wave-uniform dtype detection: 256 probe elems; f32-as-bf16 low halves
// have uniform exponents => P(all small) ~ 0.52^128 ~ 1e-36
__device__ __forceinline__ int detect_f32(const void* w) {
    const short4* p = (const short4*)w;
    short4 v = p[threadIdx.x & 63];
    int bad = 0;
    #pragma unroll
    for (int j = 0; j < 4; ++j) {
        float f = bits2f(((const unsigned short*)&v)[j]);
        if (!(fabsf(f) <= 100.0f)) bad = 1;   // catches NaN/Inf too
    }
    return __any(bad) ? 1 : 0;
}

// ---------------- weight prep ----------------
// Wst (bf16): w_in[128o][128i]@0 | wconvT[9tap][128o][128r]@16384 |
//   wqkv[384o][128i]@163840 | wg[3][128o][256k]@212992 | wout[128o][128i]@311296
// Bst f32[768]: in@0 conv@128 i@256 g@384 o@512 out@640
__global__ __launch_bounds__(256) void k_prep(
    const void* w_in, const void* w_conv, const void* wq, const void* wk, const void* wv,
    const void* w_i, const void* w_g, const void* w_o, const void* w_out,
    const void* b_in, const void* b_conv, const void* b_i, const void* b_g,
    const void* b_o, const void* b_out,
    bf16* __restrict__ Wdst, float* __restrict__ Bdst)
{
    int idx = blockIdx.x * 256 + threadIdx.x;
    const int f = detect_f32(w_in);
    if (idx < 327680) {
        const void* src; int si;
        if (idx < 16384)       { src = w_in; si = idx; }   // native [o][i]
        else if (idx < 163840) { int j = idx - 16384; int tap = j >> 14, rem = j & 16383;
                                 int o = rem >> 7, r = rem & 127;
                                 src = w_conv; si = o * 2304 + r * 9 + tap; }
        else if (idx < 212992) { int j = idx - 163840; int o = j >> 7, i = j & 127;
                                 int ws_ = o >> 7;
                                 src = ws_ == 0 ? wq : ws_ == 1 ? wk : wv;
                                 si = (o & 127) * 128 + i; }
        else if (idx < 311296) { int j = idx - 212992; int g = j >> 15, rem = j & 32767;
                                 int o = rem >> 8, k = rem & 255;
                                 src = g == 0 ? w_i : g == 1 ? w_g : w_o; si = o * 256 + k; }
        else                   { int j = idx - 311296; int o = j >> 7, i = j & 127;
                                 src = w_out; si = o * 128 + i; }
        float v = f ? ((const float*)src)[si] : b2f(((const bf16*)src)[si]);
        Wdst[idx] = __float2bfloat16(v);
    } else if (idx < 327680 + 768) {
        int j = idx - 327680; int b = j >> 7, e = j & 127;
        const void* src = b == 0 ? b_in : b == 1 ? b_conv : b == 2 ? b_i
                        : b == 3 ? b_g : b == 4 ? b_o : b_out;
        Bdst[j] = f ? ((const float*)src)[e] : b2f(((const bf16*)src)[e]);
    }
}

// ---------------- k_inm: fused transpose + MFMA GEMM + tanh ----------------
__global__ __launch_bounds__(256) void k_inm(const void* __restrict__ x,
                                             const void* __restrict__ wraw,
                                             const bf16* __restrict__ Wm,   // [o][i]
                                             const float* __restrict__ bias,
                                             bf16* __restrict__ XT) {
    __shared__ short Xl[32][132];
    const int tid = threadIdx.x, wave = tid >> 6, lane = tid & 63;
    const int quad = lane >> 4, l16 = lane & 15;
    const int n = blockIdx.z;
    const int pbase = blockIdx.x * 32;
    const int obase = blockIdx.y * 32 + (wave & 1) * 16;
    const int pstrip = (wave >> 1) * 16;
    const int f = detect_f32(wraw);

    #pragma unroll
    for (int rep = 0; rep < 4; ++rep) {
        int u = tid + rep * 256;
        int i = u >> 3;
        int p4 = (u & 7) * 4;
        int p = pbase + p4;
        short4 s = {0, 0, 0, 0};
        if (p < HW) {
            size_t gi = (size_t)n * CH * HW + (size_t)i * HW + p;
            if (f) {
                float4 fv = *(const float4*)((const float*)x + gi);
                int2 pk = pack4(fv.x, fv.y, fv.z, fv.w);
                s = *(short4*)&pk;
            } else {
                s = *(const short4*)((const bf16*)x + gi);
            }
        }
        Xl[p4 + 0][i] = s.x; Xl[p4 + 1][i] = s.y;
        Xl[p4 + 2][i] = s.z; Xl[p4 + 3][i] = s.w;
    }
    __syncthreads();

    const int pl = pstrip + l16;
    f32x4 acc = {0.f, 0.f, 0.f, 0.f};
    #pragma unroll
    for (int kc = 0; kc < 4; ++kc) {
        int k = kc * 32 + quad * 8;
        short4 b0 = *(const short4*)&Xl[pl][k];
        short4 b1 = *(const short4*)&Xl[pl][k + 4];
        frag8 bf = {b0.x, b0.y, b0.z, b0.w, b1.x, b1.y, b1.z, b1.w};
        frag8 wf = *(const frag8*)&Wm[(obase + l16) * CH + k];
        acc = __builtin_amdgcn_mfma_f32_16x16x32_bf16(wf, bf, acc, 0, 0, 0);
    }

    int p = pbase + pstrip + l16;
    if (p < HW) {
        int og = obase + quad * 4;
        int2 pk = pack4(ftanh(acc[0] + bias[og + 0]), ftanh(acc[1] + bias[og + 1]),
                        ftanh(acc[2] + bias[og + 2]), ftanh(acc[3] + bias[og + 3]));
        *(int2*)((short*)XT + ((size_t)n * HW + p) * CH + og) = pk;
    }
}

// ---------------- MFMA GEMM family, 32p x 32o blocks (wave = 16o x 16p) ----------------
// MODE 0: CONV (9 taps)  MODE 1: QKV (Q,K head-grouped; V channel-first via swap)
// MODE 2: GATES (K=256, fused cell)
template<int MODE>
__global__ __launch_bounds__(256) void k_mm(
    const bf16* __restrict__ Act, const bf16* __restrict__ Act2,
    const bf16* __restrict__ Wm, const float* __restrict__ bias,
    bf16* __restrict__ o0, bf16* __restrict__ o1, bf16* __restrict__ o2)
{
    constexpr int NW  = (MODE == 2) ? 3 : 1;
    constexpr int KW  = (MODE == 2) ? 256 : 128;
    const int tid = threadIdx.x, wave = tid >> 6, lane = tid & 63;
    const int quad = lane >> 4, l16 = lane & 15;
    const int n = blockIdx.z;
    const int obase = blockIdx.y * 32 + (wave & 1) * 16;
    const int pbase = blockIdx.x * 32 + (wave >> 1) * 16;
    if (pbase >= HW) return;                      // wave-uniform; no barriers here
    const bf16* actn = Act + (size_t)n * HW * CH;
    const bool vtile = (MODE == 1) && (obase >= 256);
    const int p1 = pbase + l16;                   // always < HW (pbase <= 1280)

    frag8 zf = {0, 0, 0, 0, 0, 0, 0, 0};
    f32x4 acc[NW];
    #pragma unroll
    for (int g = 0; g < NW; ++g) acc[g] = (f32x4){0.f, 0.f, 0.f, 0.f};

    if (MODE == 0) {
        const int h1 = p1 / 36, w1 = p1 - h1 * 36;
        for (int tap = 0; tap < 9; ++tap) {
            int dy = tap / 3 - 1, dx = tap - (tap / 3) * 3 - 1;
            bool ok1 = (unsigned)(h1 + dy) < 36u && (unsigned)(w1 + dx) < 36u;
            int sh = dy * 36 + dx;
            const bf16* a1 = actn + (size_t)(p1 + sh) * CH + quad * 8;
            const bf16* wp = Wm + tap * 16384 + (obase + l16) * CH + quad * 8;
            #pragma unroll
            for (int kc = 0; kc < 4; ++kc) {
                frag8 bf1 = zf;
                if (ok1) bf1 = *(const frag8*)&a1[kc * 32];
                frag8 wf = *(const frag8*)&wp[kc * 32];
                acc[0] = __builtin_amdgcn_mfma_f32_16x16x32_bf16(wf, bf1, acc[0], 0, 0, 0);
            }
        }
    } else {
        const bf16* act2n = (MODE == 2) ? Act2 + (size_t)n * HW * CH : nullptr;
        #pragma unroll
        for (int kc = 0; kc < KW / 32; ++kc) {
            const bf16* src = (MODE == 2 && kc >= 4) ? act2n : actn;
            int ko = (MODE == 2 ? (kc & 3) : kc) * 32 + quad * 8;
            frag8 bf1 = *(const frag8*)&src[(size_t)p1 * CH + ko];
            #pragma unroll
            for (int g = 0; g < NW; ++g) {
                const bf16* wp = Wm + g * 32768 + (obase + l16) * KW + kc * 32 + quad * 8;
                frag8 wf = *(const frag8*)wp;
                if (vtile)
                    acc[g] = __builtin_amdgcn_mfma_f32_16x16x32_bf16(bf1, wf, acc[g], 0, 0, 0);
                else
                    acc[g] = __builtin_amdgcn_mfma_f32_16x16x32_bf16(wf, bf1, acc[g], 0, 0, 0);
            }
        }
    }

    // ---- epilogue ----
    if (vtile) {
        // D^T: lane holds D[p = pbase+quad*4+r][o = (obase-256)+l16]; channel-first store
        int ov = (obase - 256) + l16;
        int p4 = pbase + quad * 4;
        int2 pk = pack4(acc[0][0], acc[0][1], acc[0][2], acc[0][3]);
        *(int2*)((short*)o2 + ((size_t)n * CH + ov) * HW + p4) = pk;
        return;
    }
    const int og = obase + quad * 4;
    size_t rowoff = ((size_t)n * HW + p1) * CH;
    if (MODE == 0) {
        int2 pk = pack4(acc[0][0] + bias[og + 0], acc[0][1] + bias[og + 1],
                        acc[0][2] + bias[og + 2], acc[0][3] + bias[og + 3]);
        *(int2*)((short*)o0 + rowoff + og) = pk;
    } else if (MODE == 1) {
        int which = og >> 7, ol = og & 127;
        bf16* dst = which == 0 ? o0 : o1;
        size_t di = (((size_t)n * 8 + (ol >> 4)) * HW + p1) * 16 + (ol & 15);
        int2 pk = pack4(acc[0][0], acc[0][1], acc[0][2], acc[0][3]);
        *(int2*)((short*)dst + di) = pk;
    } else {
        float hv[4];
        #pragma unroll
        for (int r = 0; r < 4; ++r) {
            int o = og + r;
            float iv = fsigm(acc[0][r] + bias[o]);
            float gv = ftanh(acc[1][r] + bias[128 + o]);
            float ov = fsigm(acc[2][r] + bias[256 + o]);
            hv[r] = ov * ftanh(iv * gv);
        }
        int2 pk = pack4(hv[0], hv[1], hv[2], hv[3]);
        *(int2*)((short*)o0 + rowoff + og) = pk;
    }
}

// ---------------- k_outm: out[n][o][p] = W_out h + b, 32p x 32o blocks ----------------
__global__ __launch_bounds__(256) void k_outm(const bf16* __restrict__ Hb,
                                              const bf16* __restrict__ Wm,
                                              const float* __restrict__ bias,
                                              void* __restrict__ out,
                                              const void* __restrict__ wraw) {
    const int tid = threadIdx.x, wave = tid >> 6, lane = tid & 63;
    const int quad = lane >> 4, l16 = lane & 15;
    const int n = blockIdx.z;
    const int pbase = blockIdx.x * 32 + (wave & 1) * 16;
    const int obase = blockIdx.y * 32 + (wave >> 1) * 16;
    if (pbase >= HW) return;
    const int f32f = detect_f32(wraw);
    const bf16* hn = Hb + (size_t)n * HW * CH;
    const int pa = pbase + l16;                   // always < HW

    f32x4 acc = {0.f, 0.f, 0.f, 0.f};
    #pragma unroll
    for (int kc = 0; kc < 4; ++kc) {
        int ko = kc * 32 + quad * 8;
        frag8 af = *(const frag8*)&hn[(size_t)pa * CH + ko];
        frag8 b0 = *(const frag8*)&Wm[(obase + l16) * CH + ko];
        acc = __builtin_amdgcn_mfma_f32_16x16x32_bf16(af, b0, acc, 0, 0, 0);
    }
    int p4 = pbase + quad * 4;
    int o = obase + l16;
    float bv = bias[o];
    size_t di = ((size_t)n * CH + o) * HW + p4;
    if (f32f) {
        float4 fv = {acc[0] + bv, acc[1] + bv, acc[2] + bv, acc[3] + bv};
        *(float4*)&((float*)out)[di] = fv;
    } else {
        int2 pk = pack4(acc[0] + bv, acc[1] + bv, acc[2] + bv, acc[3] + bv);
        *(int2*)&((short*)out)[di] = pk;
    }
}

// ---------------- MFMA flash attention v5: 4-way d-split, 1024 threads ----------------
// 16 waves: qw = wave&3 (16 q each), dq = wave>>2 (quarter of d-range).
// Additive no-max softmax => partials combine with one LDS exchange + one barrier.
// S^T = K Q^T (coalesced K from head-grouped global); P spill b64-packed; O^T = V^T P^T.
__global__ __launch_bounds__(1024) void k_attn(const bf16* __restrict__ Qg,
                                               const bf16* __restrict__ Kg,
                                               const bf16* __restrict__ Vcf,
                                               bf16* __restrict__ A) {
    __shared__ __align__(16) short Pl[16][16][72];   // [wave][q][d]
    __shared__ float Ocomb[3][4][16][17];            // [slot][qw][c][q]
    __shared__ float Lcomb[3][4][16];                // [slot][qw][q]

    const int tid = threadIdx.x;
    const int w = tid >> 6, lane = tid & 63;
    const int quad = lane >> 4, l16 = lane & 15;
    const int qw = w & 3, dq = w >> 2;
    const int qb = blockIdx.x * 64;
    const int head = blockIdx.y, n = blockIdx.z;
    const short* Qh = (const short*)Qg + ((size_t)(n * 8 + head)) * HW * 16;
    const short* Kh = (const short*)Kg + ((size_t)(n * 8 + head)) * HW * 16;
    const short* Vh = (const short*)Vcf + ((size_t)n * CH + head * 16) * HW;

    frag8 zf = {0, 0, 0, 0, 0, 0, 0, 0};
    frag8 qf = zf;
    const int qtok = qb + qw * 16 + l16;
    if (quad < 2 && qtok < HW)
        qf = *(const frag8*)&Qh[(size_t)qtok * 16 + quad * 8];

    f32x4 Oacc = {0.f, 0.f, 0.f, 0.f};   // O^T: lane holds O[c=quad*4+r][q=l16]
    float lsum = 0.0f;
    short* plrow = &Pl[w][l16][0];

    const int cstart = dq ? (1 + 5 * dq) : 0;   // {0,6,11,16}
    const int cend   = 6 + 5 * dq;              // {6,11,16,21}
    for (int ci = cstart; ci < cend; ++ci) {
        int d0 = ci * 64;
        bool last = (ci == 20);                  // tail: d 1280..1343, 16 valid
        f32x4 ST[4];
        #pragma unroll
        for (int t = 0; t < 4; ++t) {
            frag8 kf = zf;
            if (quad < 2)
                kf = *(const frag8*)&Kh[(size_t)(d0 + t * 16 + l16) * 16 + quad * 8];
            f32x4 zacc = {0.f, 0.f, 0.f, 0.f};
            ST[t] = __builtin_amdgcn_mfma_f32_16x16x32_bf16(kf, qf, zacc, 0, 0, 0);
        }
        #pragma unroll
        for (int t = 0; t < 4; ++t) {
            float pf0 = __expf(ST[t][0]);
            float pf1 = __expf(ST[t][1]);
            float pf2 = __expf(ST[t][2]);
            float pf3 = __expf(ST[t][3]);
            if (last) {
                int dg = d0 + t * 16 + quad * 4;
                if (dg + 0 >= HW) pf0 = 0.0f;
                if (dg + 1 >= HW) pf1 = 0.0f;
                if (dg + 2 >= HW) pf2 = 0.0f;
                if (dg + 3 >= HW) pf3 = 0.0f;
            }
            lsum += (pf0 + pf1) + (pf2 + pf3);
            *(int2*)&plrow[t * 16 + quad * 4] = pack4(pf0, pf1, pf2, pf3);
        }
        #pragma unroll
        for (int s = 0; s < 2; ++s) {
            frag8 vf = *(const frag8*)&Vh[(size_t)l16 * HW + d0 + s * 32 + quad * 8];
            frag8 pf = *(const frag8*)&plrow[s * 32 + quad * 8];
            Oacc = __builtin_amdgcn_mfma_f32_16x16x32_bf16(vf, pf, Oacc, 0, 0, 0);
        }
    }

    lsum += __shfl_xor(lsum, 16);
    lsum += __shfl_xor(lsum, 32);

    if (dq > 0) {
        int slot = dq - 1;
        #pragma unroll
        for (int r = 0; r < 4; ++r)
            Ocomb[slot][qw][quad * 4 + r][l16] = Oacc[r];
        if (quad == 0) Lcomb[slot][qw][l16] = lsum;
    }
    __syncthreads();
    if (dq == 0) {
        #pragma unroll
        for (int s = 0; s < 3; ++s) {
            #pragma unroll
            for (int r = 0; r < 4; ++r)
                Oacc[r] += Ocomb[s][qw][quad * 4 + r][l16];
            lsum += Lcomb[s][qw][l16];
        }
        if (qtok < HW) {
            float inv = frcp(lsum);
            int2 pk = pack4(Oacc[0] * inv, Oacc[1] * inv, Oacc[2] * inv, Oacc[3] * inv);
            short* An = (short*)A + (size_t)n * HW * CH;
            *(int2*)&An[(size_t)qtok * CH + head * 16 + quad * 4] = pk;
        }
    }
}

extern "C" void kernel_launch(void* const* d_in, const int* in_sizes, int n_in,
                              void* d_out, int out_size, void* d_ws, size_t ws_size,
                              hipStream_t stream) {
    char* ws = (char*)d_ws;
    bf16*  Wst  = (bf16*)(ws + 256);          // 327680 bf16
    float* Bst  = (float*)(ws + 655616);      // 768 f32
    bf16*  XT   = (bf16*)(ws + 1048576);      // channel-last [n][1296][128]
    bf16*  Zb   = XT + TT;
    bf16*  Qb   = Zb + TT;                    // head-grouped [n][8][1296][16]
    bf16*  Kb   = Qb + TT;
    bf16*  Vb   = Kb + TT;                    // channel-first [n][128][1296]
    bf16*  Ab   = Vb + TT;
    bf16*  Hb   = Ab + TT;                    // ~19.6 MB total

    k_prep<<<1284, 256, 0, stream>>>(d_in[1], d_in[3], d_in[5], d_in[6], d_in[7],
                                     d_in[8], d_in[12], d_in[14], d_in[16],
                                     d_in[2], d_in[4], d_in[9], d_in[13], d_in[15], d_in[17],
                                     Wst, Bst);
    k_inm<<<dim3(41, 4, 8), 256, 0, stream>>>(d_in[0], d_in[1], Wst, Bst, XT);
    k_mm<0><<<dim3(41, 4, 8), 256, 0, stream>>>(XT, nullptr, Wst + 16384, Bst + 128,
                                                Zb, nullptr, nullptr);
    k_mm<1><<<dim3(41, 12, 8), 256, 0, stream>>>(Zb, nullptr, Wst + 163840, nullptr,
                                                 Qb, Kb, Vb);
    k_attn<<<dim3(21, 8, 8), 1024, 0, stream>>>(Qb, Kb, Vb, Ab);
    k_mm<2><<<dim3(41, 4, 8), 256, 0, stream>>>(Zb, Ab, Wst + 212992, Bst + 256,
                                                Hb, nullptr, nullptr);
    k_outm<<<dim3(41, 4, 8), 256, 0, stream>>>(Hb, Wst + 311296, Bst + 640, d_out, d_in[1]);
}

// Round 13
// 217.338 us; speedup vs baseline: 1.0893x; 1.0893x over previous
//
#include <hip/hip_runtime.h>
#include <hip/hip_bf16.h>
#include <math.h>

typedef __hip_bfloat16 bf16;
typedef __attribute__((ext_vector_type(8))) short frag8;
typedef __attribute__((ext_vector_type(4))) float f32x4;

#define HW  1296
#define CH  128
#define TT  1327104   // 8 * 1296 * 128

__device__ __forceinline__ float b2f(bf16 v) { return __bfloat162float(v); }
__device__ __forceinline__ float bits2f(unsigned short u) {
    return __uint_as_float(((unsigned)u) << 16);
}
__device__ __forceinline__ float frcp(float x) { return __builtin_amdgcn_rcpf(x); }
__device__ __forceinline__ float fsigm(float x) { return frcp(1.0f + __expf(-x)); }
__device__ __forceinline__ float ftanh(float x) {
    float xc = fminf(15.0f, fmaxf(-15.0f, x));
    float e = __expf(2.0f * xc);
    return (e - 1.0f) * frcp(e + 1.0f);
}
// round-half-up f32->bf16 pair pack: 2 adds + 1 v_perm
__device__ __forceinline__ int packrh(float a, float b) {
    unsigned ua = __float_as_uint(a) + 0x8000u;
    unsigned ub = __float_as_uint(b) + 0x8000u;
    return (int)__builtin_amdgcn_perm(ub, ua, 0x07060302);
}
__device__ __forceinline__ int2 pack4(float a, float b, float c, float d) {
    int2 r; r.x = packrh(a, b); r.y = packrh(c, d); return r;
}

// inline wave-uniform dtype detection (256 probe elems of w_in)
__device__ __forceinline__ int detect_f32(const void* w) {
    const short4* p = (const short4*)w;
    short4 v = p[threadIdx.x & 63];
    int bad = 0;
    #pragma unroll
    for (int j = 0; j < 4; ++j) {
        float f = bits2f(((const unsigned short*)&v)[j]);
        if (!(fabsf(f) <= 100.0f)) bad = 1;   // catches NaN/Inf too
    }
    return __any(bad) ? 1 : 0;
}

// ---------------- weight prep ----------------
// Wst (bf16): w_in[128o][128i]@0 | wconvT[9tap][128o][128r]@16384 |
//   wqkv[384o][128i]@163840 | wg[3][128o][256k]@212992 | wout[128o][128i]@311296
// Bst f32[768]: in@0 conv@128 i@256 g@384 o@512 out@640
__global__ __launch_bounds__(256) void k_prep(
    const void* w_in, const void* w_conv, const void* wq, const void* wk, const void* wv,
    const void* w_i, const void* w_g, const void* w_o, const void* w_out,
    const void* b_in, const void* b_conv, const void* b_i, const void* b_g,
    const void* b_o, const void* b_out,
    bf16* __restrict__ Wdst, float* __restrict__ Bdst)
{
    int idx = blockIdx.x * 256 + threadIdx.x;
    const int f = detect_f32(w_in);
    if (idx < 327680) {
        const void* src; int si;
        if (idx < 16384)       { src = w_in; si = idx; }   // native [o][i]
        else if (idx < 163840) { int j = idx - 16384; int tap = j >> 14, rem = j & 16383;
                                 int o = rem >> 7, r = rem & 127;
                                 src = w_conv; si = o * 2304 + r * 9 + tap; }
        else if (idx < 212992) { int j = idx - 163840; int o = j >> 7, i = j & 127;
                                 int ws_ = o >> 7;
                                 src = ws_ == 0 ? wq : ws_ == 1 ? wk : wv;
                                 si = (o & 127) * 128 + i; }
        else if (idx < 311296) { int j = idx - 212992; int g = j >> 15, rem = j & 32767;
                                 int o = rem >> 8, k = rem & 255;
                                 src = g == 0 ? w_i : g == 1 ? w_g : w_o; si = o * 256 + k; }
        else                   { int j = idx - 311296; int o = j >> 7, i = j & 127;
                                 src = w_out; si = o * 128 + i; }
        float v = f ? ((const float*)src)[si] : b2f(((const bf16*)src)[si]);
        Wdst[idx] = __float2bfloat16(v);
    } else if (idx < 327680 + 768) {
        int j = idx - 327680; int b = j >> 7, e = j & 127;
        const void* src = b == 0 ? b_in : b == 1 ? b_conv : b == 2 ? b_i
                        : b == 3 ? b_g : b == 4 ? b_o : b_out;
        Bdst[j] = f ? ((const float*)src)[e] : b2f(((const bf16*)src)[e]);
    }
}

// ---------------- k_inm: fused transpose + MFMA GEMM + tanh ----------------
__global__ __launch_bounds__(256) void k_inm(const void* __restrict__ x,
                                             const void* __restrict__ wraw,
                                             const bf16* __restrict__ Wm,   // [o][i]
                                             const float* __restrict__ bias,
                                             bf16* __restrict__ XT) {
    __shared__ short Xl[32][132];
    const int tid = threadIdx.x, wave = tid >> 6, lane = tid & 63;
    const int quad = lane >> 4, l16 = lane & 15;
    const int n = blockIdx.z;
    const int pbase = blockIdx.x * 32;
    const int obase = blockIdx.y * 32 + (wave & 1) * 16;
    const int pstrip = (wave >> 1) * 16;
    const int f = detect_f32(wraw);

    #pragma unroll
    for (int rep = 0; rep < 4; ++rep) {
        int u = tid + rep * 256;
        int i = u >> 3;
        int p4 = (u & 7) * 4;
        int p = pbase + p4;
        short4 s = {0, 0, 0, 0};
        if (p < HW) {
            size_t gi = (size_t)n * CH * HW + (size_t)i * HW + p;
            if (f) {
                float4 fv = *(const float4*)((const float*)x + gi);
                int2 pk = pack4(fv.x, fv.y, fv.z, fv.w);
                s = *(short4*)&pk;
            } else {
                s = *(const short4*)((const bf16*)x + gi);
            }
        }
        Xl[p4 + 0][i] = s.x; Xl[p4 + 1][i] = s.y;
        Xl[p4 + 2][i] = s.z; Xl[p4 + 3][i] = s.w;
    }
    __syncthreads();

    const int pl = pstrip + l16;
    f32x4 acc = {0.f, 0.f, 0.f, 0.f};
    #pragma unroll
    for (int kc = 0; kc < 4; ++kc) {
        int k = kc * 32 + quad * 8;
        short4 b0 = *(const short4*)&Xl[pl][k];
        short4 b1 = *(const short4*)&Xl[pl][k + 4];
        frag8 bf = {b0.x, b0.y, b0.z, b0.w, b1.x, b1.y, b1.z, b1.w};
        frag8 wf = *(const frag8*)&Wm[(obase + l16) * CH + k];
        acc = __builtin_amdgcn_mfma_f32_16x16x32_bf16(wf, bf, acc, 0, 0, 0);
    }

    int p = pbase + pstrip + l16;
    if (p < HW) {
        int og = obase + quad * 4;
        int2 pk = pack4(ftanh(acc[0] + bias[og + 0]), ftanh(acc[1] + bias[og + 1]),
                        ftanh(acc[2] + bias[og + 2]), ftanh(acc[3] + bias[og + 3]));
        *(int2*)((short*)XT + ((size_t)n * HW + p) * CH + og) = pk;
    }
}

// ---------------- MFMA GEMM family, 64p x 32o blocks (wave = 16o x 32p, 2 p-frags) ------
// MODE 0: CONV (9 taps, unrolled)  MODE 1: QKV (Q,K head-grouped; V channel-first via swap)
// MODE 2: GATES (K=256, fused cell)
template<int MODE>
__global__ __launch_bounds__(256) void k_mm(
    const bf16* __restrict__ Act, const bf16* __restrict__ Act2,
    const bf16* __restrict__ Wm, const float* __restrict__ bias,
    bf16* __restrict__ o0, bf16* __restrict__ o1, bf16* __restrict__ o2)
{
    constexpr int NW  = (MODE == 2) ? 3 : 1;
    constexpr int KW  = (MODE == 2) ? 256 : 128;
    const int tid = threadIdx.x, wave = tid >> 6, lane = tid & 63;
    const int quad = lane >> 4, l16 = lane & 15;
    const int ostrip = wave & 1, pstrip = wave >> 1;
    const int n = blockIdx.z;
    const int obase = blockIdx.y * 32 + ostrip * 16;
    const int pbase = blockIdx.x * 64 + pstrip * 32;
    const bf16* actn = Act + (size_t)n * HW * CH;
    const bool vtile = (MODE == 1) && (obase >= 256);   // wave-uniform

    const int p1 = pbase + l16, p2 = pbase + 16 + l16;
    const bool p1ok = p1 < HW, p2ok = p2 < HW;

    frag8 zf = {0, 0, 0, 0, 0, 0, 0, 0};
    f32x4 acc[NW][2];
    #pragma unroll
    for (int g = 0; g < NW; ++g) {
        acc[g][0] = (f32x4){0.f, 0.f, 0.f, 0.f};
        acc[g][1] = (f32x4){0.f, 0.f, 0.f, 0.f};
    }

    if (MODE == 0) {
        const int h1 = p1 / 36, w1 = p1 - h1 * 36;
        const int h2 = p2 / 36, w2 = p2 - h2 * 36;
        #pragma unroll                      // unrolled: 72 independent loads visible
        for (int tap = 0; tap < 9; ++tap) {
            int dy = tap / 3 - 1, dx = tap - (tap / 3) * 3 - 1;
            bool ok1 = p1ok && (unsigned)(h1 + dy) < 36u && (unsigned)(w1 + dx) < 36u;
            bool ok2 = p2ok && (unsigned)(h2 + dy) < 36u && (unsigned)(w2 + dx) < 36u;
            int sh = dy * 36 + dx;
            const bf16* a1 = actn + (size_t)(p1 + sh) * CH + quad * 8;
            const bf16* a2 = actn + (size_t)(p2 + sh) * CH + quad * 8;
            const bf16* wp = Wm + tap * 16384 + (obase + l16) * CH + quad * 8;
            #pragma unroll
            for (int kc = 0; kc < 4; ++kc) {
                frag8 bf1 = zf, bf2 = zf;
                if (ok1) bf1 = *(const frag8*)&a1[kc * 32];
                if (ok2) bf2 = *(const frag8*)&a2[kc * 32];
                frag8 wf = *(const frag8*)&wp[kc * 32];
                acc[0][0] = __builtin_amdgcn_mfma_f32_16x16x32_bf16(wf, bf1, acc[0][0], 0, 0, 0);
                acc[0][1] = __builtin_amdgcn_mfma_f32_16x16x32_bf16(wf, bf2, acc[0][1], 0, 0, 0);
            }
        }
    } else {
        const bf16* act2n = (MODE == 2) ? Act2 + (size_t)n * HW * CH : nullptr;
        #pragma unroll
        for (int kc = 0; kc < KW / 32; ++kc) {
            const bf16* src = (MODE == 2 && kc >= 4) ? act2n : actn;
            int ko = (MODE == 2 ? (kc & 3) : kc) * 32 + quad * 8;
            frag8 bf1 = zf, bf2 = zf;
            if (p1ok) bf1 = *(const frag8*)&src[(size_t)p1 * CH + ko];
            if (p2ok) bf2 = *(const frag8*)&src[(size_t)p2 * CH + ko];
            #pragma unroll
            for (int g = 0; g < NW; ++g) {
                const bf16* wp = Wm + g * 32768 + (obase + l16) * KW + kc * 32 + quad * 8;
                frag8 wf = *(const frag8*)wp;
                if (vtile) {
                    acc[g][0] = __builtin_amdgcn_mfma_f32_16x16x32_bf16(bf1, wf, acc[g][0], 0, 0, 0);
                    acc[g][1] = __builtin_amdgcn_mfma_f32_16x16x32_bf16(bf2, wf, acc[g][1], 0, 0, 0);
                } else {
                    acc[g][0] = __builtin_amdgcn_mfma_f32_16x16x32_bf16(wf, bf1, acc[g][0], 0, 0, 0);
                    acc[g][1] = __builtin_amdgcn_mfma_f32_16x16x32_bf16(wf, bf2, acc[g][1], 0, 0, 0);
                }
            }
        }
    }

    // ---- epilogue ----
    if (vtile) {
        // D^T: lane holds D[p][o]; store channel-first
        int ov = (obase - 256) + l16;
        #pragma unroll
        for (int pt = 0; pt < 2; ++pt) {
            int p4 = pbase + pt * 16 + quad * 4;
            if (p4 >= HW) continue;
            int2 pk = pack4(acc[0][pt][0], acc[0][pt][1], acc[0][pt][2], acc[0][pt][3]);
            *(int2*)((short*)o2 + ((size_t)n * CH + ov) * HW + p4) = pk;
        }
        return;
    }
    const int og = obase + quad * 4;
    #pragma unroll
    for (int pt = 0; pt < 2; ++pt) {
        int p = pbase + pt * 16 + l16;
        if (p >= HW) continue;
        size_t rowoff = ((size_t)n * HW + p) * CH;
        if (MODE == 0) {
            int2 pk = pack4(acc[0][pt][0] + bias[og + 0], acc[0][pt][1] + bias[og + 1],
                            acc[0][pt][2] + bias[og + 2], acc[0][pt][3] + bias[og + 3]);
            *(int2*)((short*)o0 + rowoff + og) = pk;
        } else if (MODE == 1) {
            int which = og >> 7, ol = og & 127;
            bf16* dst = which == 0 ? o0 : o1;
            size_t di = (((size_t)n * 8 + (ol >> 4)) * HW + p) * 16 + (ol & 15);
            int2 pk = pack4(acc[0][pt][0], acc[0][pt][1], acc[0][pt][2], acc[0][pt][3]);
            *(int2*)((short*)dst + di) = pk;
        } else {
            float hv[4];
            #pragma unroll
            for (int r = 0; r < 4; ++r) {
                int o = og + r;
                float iv = fsigm(acc[0][pt][r] + bias[o]);
                float gv = ftanh(acc[1][pt][r] + bias[128 + o]);
                float ov = fsigm(acc[2][pt][r] + bias[256 + o]);
                hv[r] = ov * ftanh(iv * gv);
            }
            int2 pk = pack4(hv[0], hv[1], hv[2], hv[3]);
            *(int2*)((short*)o0 + rowoff + og) = pk;
        }
    }
}

// ---------------- k_outm: out[n][o][p] = W_out h + b (channel-first store) ----------------
__global__ __launch_bounds__(256) void k_outm(const bf16* __restrict__ Hb,
                                              const bf16* __restrict__ Wm,
                                              const float* __restrict__ bias,
                                              void* __restrict__ out,
                                              const void* __restrict__ wraw) {
    const int tid = threadIdx.x, wave = tid >> 6, lane = tid & 63;
    const int quad = lane >> 4, l16 = lane & 15;
    const int pstrip = wave & 1, ostrip = wave >> 1;
    const int n = blockIdx.z;
    const int pbase = blockIdx.x * 32 + pstrip * 16;
    const int obase = blockIdx.y * 64 + ostrip * 32;
    if (pbase >= HW) return;
    const int f32f = detect_f32(wraw);
    const bf16* hn = Hb + (size_t)n * HW * CH;
    const int pa = pbase + l16;

    f32x4 acc0 = {0.f, 0.f, 0.f, 0.f}, acc1 = {0.f, 0.f, 0.f, 0.f};
    #pragma unroll
    for (int kc = 0; kc < 4; ++kc) {
        int ko = kc * 32 + quad * 8;
        frag8 af = *(const frag8*)&hn[(size_t)pa * CH + ko];
        frag8 b0 = *(const frag8*)&Wm[(obase + l16) * CH + ko];
        frag8 b1 = *(const frag8*)&Wm[(obase + 16 + l16) * CH + ko];
        acc0 = __builtin_amdgcn_mfma_f32_16x16x32_bf16(af, b0, acc0, 0, 0, 0);
        acc1 = __builtin_amdgcn_mfma_f32_16x16x32_bf16(af, b1, acc1, 0, 0, 0);
    }
    int p4 = pbase + quad * 4;
    #pragma unroll
    for (int ot = 0; ot < 2; ++ot) {
        int o = obase + ot * 16 + l16;
        f32x4 a = ot ? acc1 : acc0;
        float bv = bias[o];
        size_t di = ((size_t)n * CH + o) * HW + p4;
        if (f32f) {
            float4 fv = {a[0] + bv, a[1] + bv, a[2] + bv, a[3] + bv};
            *(float4*)&((float*)out)[di] = fv;
        } else {
            int2 pk = pack4(a[0] + bv, a[1] + bv, a[2] + bv, a[3] + bv);
            *(int2*)&((short*)out)[di] = pk;
        }
    }
}

// ---------------- MFMA flash attention v5: 4-way d-split, 1024 threads ----------------
__global__ __launch_bounds__(1024) void k_attn(const bf16* __restrict__ Qg,
                                               const bf16* __restrict__ Kg,
                                               const bf16* __restrict__ Vcf,
                                               bf16* __restrict__ A) {
    __shared__ __align__(16) short Pl[16][16][72];   // [wave][q][d]
    __shared__ float Ocomb[3][4][16][17];            // [slot][qw][c][q]
    __shared__ float Lcomb[3][4][16];                // [slot][qw][q]

    const int tid = threadIdx.x;
    const int w = tid >> 6, lane = tid & 63;
    const int quad = lane >> 4, l16 = lane & 15;
    const int qw = w & 3, dq = w >> 2;
    const int qb = blockIdx.x * 64;
    const int head = blockIdx.y, n = blockIdx.z;
    const short* Qh = (const short*)Qg + ((size_t)(n * 8 + head)) * HW * 16;
    const short* Kh = (const short*)Kg + ((size_t)(n * 8 + head)) * HW * 16;
    const short* Vh = (const short*)Vcf + ((size_t)n * CH + head * 16) * HW;

    frag8 zf = {0, 0, 0, 0, 0, 0, 0, 0};
    frag8 qf = zf;
    const int qtok = qb + qw * 16 + l16;
    if (quad < 2 && qtok < HW)
        qf = *(const frag8*)&Qh[(size_t)qtok * 16 + quad * 8];

    f32x4 Oacc = {0.f, 0.f, 0.f, 0.f};   // O^T: lane holds O[c=quad*4+r][q=l16]
    float lsum = 0.0f;
    short* plrow = &Pl[w][l16][0];

    const int cstart = dq ? (1 + 5 * dq) : 0;   // {0,6,11,16}
    const int cend   = 6 + 5 * dq;              // {6,11,16,21}
    for (int ci = cstart; ci < cend; ++ci) {
        int d0 = ci * 64;
        bool last = (ci == 20);                  // tail: 16 valid d
        f32x4 ST[4];
        #pragma unroll
        for (int t = 0; t < 4; ++t) {
            frag8 kf = zf;
            if (quad < 2)
                kf = *(const frag8*)&Kh[(size_t)(d0 + t * 16 + l16) * 16 + quad * 8];
            f32x4 zacc = {0.f, 0.f, 0.f, 0.f};
            ST[t] = __builtin_amdgcn_mfma_f32_16x16x32_bf16(kf, qf, zacc, 0, 0, 0);
        }
        #pragma unroll
        for (int t = 0; t < 4; ++t) {
            float pf0 = __expf(ST[t][0]);
            float pf1 = __expf(ST[t][1]);
            float pf2 = __expf(ST[t][2]);
            float pf3 = __expf(ST[t][3]);
            if (last) {
                int dg = d0 + t * 16 + quad * 4;
                if (dg + 0 >= HW) pf0 = 0.0f;
                if (dg + 1 >= HW) pf1 = 0.0f;
                if (dg + 2 >= HW) pf2 = 0.0f;
                if (dg + 3 >= HW) pf3 = 0.0f;
            }
            lsum += (pf0 + pf1) + (pf2 + pf3);
            *(int2*)&plrow[t * 16 + quad * 4] = pack4(pf0, pf1, pf2, pf3);
        }
        #pragma unroll
        for (int s = 0; s < 2; ++s) {
            frag8 vf = *(const frag8*)&Vh[(size_t)l16 * HW + d0 + s * 32 + quad * 8];
            frag8 pf = *(const frag8*)&plrow[s * 32 + quad * 8];
            Oacc = __builtin_amdgcn_mfma_f32_16x16x32_bf16(vf, pf, Oacc, 0, 0, 0);
        }
    }

    lsum += __shfl_xor(lsum, 16);
    lsum += __shfl_xor(lsum, 32);

    if (dq > 0) {
        int slot = dq - 1;
        #pragma unroll
        for (int r = 0; r < 4; ++r)
            Ocomb[slot][qw][quad * 4 + r][l16] = Oacc[r];
        if (quad == 0) Lcomb[slot][qw][l16] = lsum;
    }
    __syncthreads();
    if (dq == 0) {
        #pragma unroll
        for (int s = 0; s < 3; ++s) {
            #pragma unroll
            for (int r = 0; r < 4; ++r)
                Oacc[r] += Ocomb[s][qw][quad * 4 + r][l16];
            lsum += Lcomb[s][qw][l16];
        }
        if (qtok < HW) {
            float inv = frcp(lsum);
            int2 pk = pack4(Oacc[0] * inv, Oacc[1] * inv, Oacc[2] * inv, Oacc[3] * inv);
            short* An = (short*)A + (size_t)n * HW * CH;
            *(int2*)&An[(size_t)qtok * CH + head * 16 + quad * 4] = pk;
        }
    }
}

extern "C" void kernel_launch(void* const* d_in, const int* in_sizes, int n_in,
                              void* d_out, int out_size, void* d_ws, size_t ws_size,
                              hipStream_t stream) {
    char* ws = (char*)d_ws;
    bf16*  Wst  = (bf16*)(ws + 256);          // 327680 bf16
    float* Bst  = (float*)(ws + 655616);      // 768 f32
    bf16*  XT   = (bf16*)(ws + 1048576);      // channel-last [n][1296][128]
    bf16*  Zb   = XT + TT;
    bf16*  Qb   = Zb + TT;                    // head-grouped [n][8][1296][16]
    bf16*  Kb   = Qb + TT;
    bf16*  Vb   = Kb + TT;                    // channel-first [n][128][1296]
    bf16*  Ab   = Vb + TT;
    bf16*  Hb   = Ab + TT;                    // ~19.6 MB total

    k_prep<<<1284, 256, 0, stream>>>(d_in[1], d_in[3], d_in[5], d_in[6], d_in[7],
                                     d_in[8], d_in[12], d_in[14], d_in[16],
                                     d_in[2], d_in[4], d_in[9], d_in[13], d_in[15], d_in[17],
                                     Wst, Bst);
    k_inm<<<dim3(41, 4, 8), 256, 0, stream>>>(d_in[0], d_in[1], Wst, Bst, XT);
    k_mm<0><<<dim3(21, 4, 8), 256, 0, stream>>>(XT, nullptr, Wst + 16384, Bst + 128,
                                                Zb, nullptr, nullptr);
    k_mm<1><<<dim3(21, 12, 8), 256, 0, stream>>>(Zb, nullptr, Wst + 163840, nullptr,
                                                 Qb, Kb, Vb);
    k_attn<<<dim3(21, 8, 8), 1024, 0, stream>>>(Qb, Kb, Vb, Ab);
    k_mm<2><<<dim3(21, 4, 8), 256, 0, stream>>>(Zb, Ab, Wst + 212992, Bst + 256,
                                                Hb, nullptr, nullptr);
    k_outm<<<dim3(41, 2, 8), 256, 0, stream>>>(Hb, Wst + 311296, Bst + 640, d_out, d_in[1]);
}

// Round 14
// 211.669 us; speedup vs baseline: 1.1185x; 1.0268x over previous
//
#include <hip/hip_runtime.h>
#include <hip/hip_bf16.h>
#include <math.h>

typedef __hip_bfloat16 bf16;
typedef __attribute__((ext_vector_type(8))) short frag8;
typedef __attribute__((ext_vector_type(4))) float f32x4;

#define HW  1296
#define CH  128
#define TT  1327104   // 8 * 1296 * 128

__device__ __forceinline__ float b2f(bf16 v) { return __bfloat162float(v); }
__device__ __forceinline__ float bits2f(unsigned short u) {
    return __uint_as_float(((unsigned)u) << 16);
}
__device__ __forceinline__ float frcp(float x) { return __builtin_amdgcn_rcpf(x); }
__device__ __forceinline__ float fsigm(float x) { return frcp(1.0f + __expf(-x)); }
__device__ __forceinline__ float ftanh(float x) {
    float xc = fminf(15.0f, fmaxf(-15.0f, x));
    float e = __expf(2.0f * xc);
    return (e - 1.0f) * frcp(e + 1.0f);
}
// round-half-up f32->bf16 pair pack: 2 adds + 1 v_perm
__device__ __forceinline__ int packrh(float a, float b) {
    unsigned ua = __float_as_uint(a) + 0x8000u;
    unsigned ub = __float_as_uint(b) + 0x8000u;
    return (int)__builtin_amdgcn_perm(ub, ua, 0x07060302);
}
__device__ __forceinline__ int2 pack4(float a, float b, float c, float d) {
    int2 r; r.x = packrh(a, b); r.y = packrh(c, d); return r;
}

// inline wave-uniform dtype detection (256 probe elems of w_in)
__device__ __forceinline__ int detect_f32(const void* w) {
    const short4* p = (const short4*)w;
    short4 v = p[threadIdx.x & 63];
    int bad = 0;
    #pragma unroll
    for (int j = 0; j < 4; ++j) {
        float f = bits2f(((const unsigned short*)&v)[j]);
        if (!(fabsf(f) <= 100.0f)) bad = 1;   // catches NaN/Inf too
    }
    return __any(bad) ? 1 : 0;
}

// ---------------- weight prep ----------------
// Wst (bf16): w_in[128o][128i]@0 | wconvT[9tap][128o][128r]@16384 |
//   wqkv[384o][128i]@163840 | wg[3][128o][256k]@212992 | wout[128o][128i]@311296
// Bst f32[768]: in@0 conv@128 i@256 g@384 o@512 out@640
__global__ __launch_bounds__(256) void k_prep(
    const void* w_in, const void* w_conv, const void* wq, const void* wk, const void* wv,
    const void* w_i, const void* w_g, const void* w_o, const void* w_out,
    const void* b_in, const void* b_conv, const void* b_i, const void* b_g,
    const void* b_o, const void* b_out,
    bf16* __restrict__ Wdst, float* __restrict__ Bdst)
{
    int idx = blockIdx.x * 256 + threadIdx.x;
    const int f = detect_f32(w_in);
    if (idx < 327680) {
        const void* src; int si;
        if (idx < 16384)       { src = w_in; si = idx; }   // native [o][i]
        else if (idx < 163840) { int j = idx - 16384; int tap = j >> 14, rem = j & 16383;
                                 int o = rem >> 7, r = rem & 127;
                                 src = w_conv; si = o * 2304 + r * 9 + tap; }
        else if (idx < 212992) { int j = idx - 163840; int o = j >> 7, i = j & 127;
                                 int ws_ = o >> 7;
                                 src = ws_ == 0 ? wq : ws_ == 1 ? wk : wv;
                                 si = (o & 127) * 128 + i; }
        else if (idx < 311296) { int j = idx - 212992; int g = j >> 15, rem = j & 32767;
                                 int o = rem >> 8, k = rem & 255;
                                 src = g == 0 ? w_i : g == 1 ? w_g : w_o; si = o * 256 + k; }
        else                   { int j = idx - 311296; int o = j >> 7, i = j & 127;
                                 src = w_out; si = o * 128 + i; }
        float v = f ? ((const float*)src)[si] : b2f(((const bf16*)src)[si]);
        Wdst[idx] = __float2bfloat16(v);
    } else if (idx < 327680 + 768) {
        int j = idx - 327680; int b = j >> 7, e = j & 127;
        const void* src = b == 0 ? b_in : b == 1 ? b_conv : b == 2 ? b_i
                        : b == 3 ? b_g : b == 4 ? b_o : b_out;
        Bdst[j] = f ? ((const float*)src)[e] : b2f(((const bf16*)src)[e]);
    }
}

// ---------------- k_inm: fused transpose + MFMA GEMM + tanh ----------------
// grid (8 n, 41 ptile, 4 otile) — n on blockIdx.x => all blocks of a batch land
// on one XCD (linear wg id % 8 == n), keeping the activation slab in one L2.
__global__ __launch_bounds__(256) void k_inm(const void* __restrict__ x,
                                             const void* __restrict__ wraw,
                                             const bf16* __restrict__ Wm,   // [o][i]
                                             const float* __restrict__ bias,
                                             bf16* __restrict__ XT) {
    __shared__ short Xl[32][132];
    const int tid = threadIdx.x, wave = tid >> 6, lane = tid & 63;
    const int quad = lane >> 4, l16 = lane & 15;
    const int n = blockIdx.x;
    const int pbase = blockIdx.y * 32;
    const int obase = blockIdx.z * 32 + (wave & 1) * 16;
    const int pstrip = (wave >> 1) * 16;
    const int f = detect_f32(wraw);

    #pragma unroll
    for (int rep = 0; rep < 4; ++rep) {
        int u = tid + rep * 256;
        int i = u >> 3;
        int p4 = (u & 7) * 4;
        int p = pbase + p4;
        short4 s = {0, 0, 0, 0};
        if (p < HW) {
            size_t gi = (size_t)n * CH * HW + (size_t)i * HW + p;
            if (f) {
                float4 fv = *(const float4*)((const float*)x + gi);
                int2 pk = pack4(fv.x, fv.y, fv.z, fv.w);
                s = *(short4*)&pk;
            } else {
                s = *(const short4*)((const bf16*)x + gi);
            }
        }
        Xl[p4 + 0][i] = s.x; Xl[p4 + 1][i] = s.y;
        Xl[p4 + 2][i] = s.z; Xl[p4 + 3][i] = s.w;
    }
    __syncthreads();

    const int pl = pstrip + l16;
    f32x4 acc = {0.f, 0.f, 0.f, 0.f};
    #pragma unroll
    for (int kc = 0; kc < 4; ++kc) {
        int k = kc * 32 + quad * 8;
        short4 b0 = *(const short4*)&Xl[pl][k];
        short4 b1 = *(const short4*)&Xl[pl][k + 4];
        frag8 bf = {b0.x, b0.y, b0.z, b0.w, b1.x, b1.y, b1.z, b1.w};
        frag8 wf = *(const frag8*)&Wm[(obase + l16) * CH + k];
        acc = __builtin_amdgcn_mfma_f32_16x16x32_bf16(wf, bf, acc, 0, 0, 0);
    }

    int p = pbase + pstrip + l16;
    if (p < HW) {
        int og = obase + quad * 4;
        int2 pk = pack4(ftanh(acc[0] + bias[og + 0]), ftanh(acc[1] + bias[og + 1]),
                        ftanh(acc[2] + bias[og + 2]), ftanh(acc[3] + bias[og + 3]));
        *(int2*)((short*)XT + ((size_t)n * HW + p) * CH + og) = pk;
    }
}

// ---------------- MFMA GEMM family, 64p x 32o blocks (wave = 16o x 32p, 2 p-frags) ------
// grid (8 n, 21 ptile, y otile) — XCD-local per batch.
// MODE 0: CONV (9 taps, unrolled)  MODE 1: QKV (Q,K head-grouped; V channel-first via swap)
// MODE 2: GATES (K=256, fused cell)
template<int MODE>
__global__ __launch_bounds__(256) void k_mm(
    const bf16* __restrict__ Act, const bf16* __restrict__ Act2,
    const bf16* __restrict__ Wm, const float* __restrict__ bias,
    bf16* __restrict__ o0, bf16* __restrict__ o1, bf16* __restrict__ o2)
{
    constexpr int NW  = (MODE == 2) ? 3 : 1;
    constexpr int KW  = (MODE == 2) ? 256 : 128;
    const int tid = threadIdx.x, wave = tid >> 6, lane = tid & 63;
    const int quad = lane >> 4, l16 = lane & 15;
    const int ostrip = wave & 1, pstrip = wave >> 1;
    const int n = blockIdx.x;
    const int obase = blockIdx.z * 32 + ostrip * 16;
    const int pbase = blockIdx.y * 64 + pstrip * 32;
    const bf16* actn = Act + (size_t)n * HW * CH;
    const bool vtile = (MODE == 1) && (obase >= 256);   // wave-uniform

    const int p1 = pbase + l16, p2 = pbase + 16 + l16;
    const bool p1ok = p1 < HW, p2ok = p2 < HW;

    frag8 zf = {0, 0, 0, 0, 0, 0, 0, 0};
    f32x4 acc[NW][2];
    #pragma unroll
    for (int g = 0; g < NW; ++g) {
        acc[g][0] = (f32x4){0.f, 0.f, 0.f, 0.f};
        acc[g][1] = (f32x4){0.f, 0.f, 0.f, 0.f};
    }

    if (MODE == 0) {
        const int h1 = p1 / 36, w1 = p1 - h1 * 36;
        const int h2 = p2 / 36, w2 = p2 - h2 * 36;
        #pragma unroll
        for (int tap = 0; tap < 9; ++tap) {
            int dy = tap / 3 - 1, dx = tap - (tap / 3) * 3 - 1;
            bool ok1 = p1ok && (unsigned)(h1 + dy) < 36u && (unsigned)(w1 + dx) < 36u;
            bool ok2 = p2ok && (unsigned)(h2 + dy) < 36u && (unsigned)(w2 + dx) < 36u;
            int sh = dy * 36 + dx;
            const bf16* a1 = actn + (size_t)(p1 + sh) * CH + quad * 8;
            const bf16* a2 = actn + (size_t)(p2 + sh) * CH + quad * 8;
            const bf16* wp = Wm + tap * 16384 + (obase + l16) * CH + quad * 8;
            #pragma unroll
            for (int kc = 0; kc < 4; ++kc) {
                frag8 bf1 = zf, bf2 = zf;
                if (ok1) bf1 = *(const frag8*)&a1[kc * 32];
                if (ok2) bf2 = *(const frag8*)&a2[kc * 32];
                frag8 wf = *(const frag8*)&wp[kc * 32];
                acc[0][0] = __builtin_amdgcn_mfma_f32_16x16x32_bf16(wf, bf1, acc[0][0], 0, 0, 0);
                acc[0][1] = __builtin_amdgcn_mfma_f32_16x16x32_bf16(wf, bf2, acc[0][1], 0, 0, 0);
            }
        }
    } else {
        const bf16* act2n = (MODE == 2) ? Act2 + (size_t)n * HW * CH : nullptr;
        #pragma unroll
        for (int kc = 0; kc < KW / 32; ++kc) {
            const bf16* src = (MODE == 2 && kc >= 4) ? act2n : actn;
            int ko = (MODE == 2 ? (kc & 3) : kc) * 32 + quad * 8;
            frag8 bf1 = zf, bf2 = zf;
            if (p1ok) bf1 = *(const frag8*)&src[(size_t)p1 * CH + ko];
            if (p2ok) bf2 = *(const frag8*)&src[(size_t)p2 * CH + ko];
            #pragma unroll
            for (int g = 0; g < NW; ++g) {
                const bf16* wp = Wm + g * 32768 + (obase + l16) * KW + kc * 32 + quad * 8;
                frag8 wf = *(const frag8*)wp;
                if (vtile) {
                    acc[g][0] = __builtin_amdgcn_mfma_f32_16x16x32_bf16(bf1, wf, acc[g][0], 0, 0, 0);
                    acc[g][1] = __builtin_amdgcn_mfma_f32_16x16x32_bf16(bf2, wf, acc[g][1], 0, 0, 0);
                } else {
                    acc[g][0] = __builtin_amdgcn_mfma_f32_16x16x32_bf16(wf, bf1, acc[g][0], 0, 0, 0);
                    acc[g][1] = __builtin_amdgcn_mfma_f32_16x16x32_bf16(wf, bf2, acc[g][1], 0, 0, 0);
                }
            }
        }
    }

    // ---- epilogue ----
    if (vtile) {
        int ov = (obase - 256) + l16;
        #pragma unroll
        for (int pt = 0; pt < 2; ++pt) {
            int p4 = pbase + pt * 16 + quad * 4;
            if (p4 >= HW) continue;
            int2 pk = pack4(acc[0][pt][0], acc[0][pt][1], acc[0][pt][2], acc[0][pt][3]);
            *(int2*)((short*)o2 + ((size_t)n * CH + ov) * HW + p4) = pk;
        }
        return;
    }
    const int og = obase + quad * 4;
    #pragma unroll
    for (int pt = 0; pt < 2; ++pt) {
        int p = pbase + pt * 16 + l16;
        if (p >= HW) continue;
        size_t rowoff = ((size_t)n * HW + p) * CH;
        if (MODE == 0) {
            int2 pk = pack4(acc[0][pt][0] + bias[og + 0], acc[0][pt][1] + bias[og + 1],
                            acc[0][pt][2] + bias[og + 2], acc[0][pt][3] + bias[og + 3]);
            *(int2*)((short*)o0 + rowoff + og) = pk;
        } else if (MODE == 1) {
            int which = og >> 7, ol = og & 127;
            bf16* dst = which == 0 ? o0 : o1;
            size_t di = (((size_t)n * 8 + (ol >> 4)) * HW + p) * 16 + (ol & 15);
            int2 pk = pack4(acc[0][pt][0], acc[0][pt][1], acc[0][pt][2], acc[0][pt][3]);
            *(int2*)((short*)dst + di) = pk;
        } else {
            float hv[4];
            #pragma unroll
            for (int r = 0; r < 4; ++r) {
                int o = og + r;
                float iv = fsigm(acc[0][pt][r] + bias[o]);
                float gv = ftanh(acc[1][pt][r] + bias[128 + o]);
                float ov = fsigm(acc[2][pt][r] + bias[256 + o]);
                hv[r] = ov * ftanh(iv * gv);
            }
            int2 pk = pack4(hv[0], hv[1], hv[2], hv[3]);
            *(int2*)((short*)o0 + rowoff + og) = pk;
        }
    }
}

// ---------------- k_outm: out[n][o][p] = W_out h + b (channel-first store) ----------------
// grid (8 n, 41 ptile, 2 otile)
__global__ __launch_bounds__(256) void k_outm(const bf16* __restrict__ Hb,
                                              const bf16* __restrict__ Wm,
                                              const float* __restrict__ bias,
                                              void* __restrict__ out,
                                              const void* __restrict__ wraw) {
    const int tid = threadIdx.x, wave = tid >> 6, lane = tid & 63;
    const int quad = lane >> 4, l16 = lane & 15;
    const int pstrip = wave & 1, ostrip = wave >> 1;
    const int n = blockIdx.x;
    const int pbase = blockIdx.y * 32 + pstrip * 16;
    const int obase = blockIdx.z * 64 + ostrip * 32;
    if (pbase >= HW) return;
    const int f32f = detect_f32(wraw);
    const bf16* hn = Hb + (size_t)n * HW * CH;
    const int pa = pbase + l16;

    f32x4 acc0 = {0.f, 0.f, 0.f, 0.f}, acc1 = {0.f, 0.f, 0.f, 0.f};
    #pragma unroll
    for (int kc = 0; kc < 4; ++kc) {
        int ko = kc * 32 + quad * 8;
        frag8 af = *(const frag8*)&hn[(size_t)pa * CH + ko];
        frag8 b0 = *(const frag8*)&Wm[(obase + l16) * CH + ko];
        frag8 b1 = *(const frag8*)&Wm[(obase + 16 + l16) * CH + ko];
        acc0 = __builtin_amdgcn_mfma_f32_16x16x32_bf16(af, b0, acc0, 0, 0, 0);
        acc1 = __builtin_amdgcn_mfma_f32_16x16x32_bf16(af, b1, acc1, 0, 0, 0);
    }
    int p4 = pbase + quad * 4;
    #pragma unroll
    for (int ot = 0; ot < 2; ++ot) {
        int o = obase + ot * 16 + l16;
        f32x4 a = ot ? acc1 : acc0;
        float bv = bias[o];
        size_t di = ((size_t)n * CH + o) * HW + p4;
        if (f32f) {
            float4 fv = {a[0] + bv, a[1] + bv, a[2] + bv, a[3] + bv};
            *(float4*)&((float*)out)[di] = fv;
        } else {
            int2 pk = pack4(a[0] + bv, a[1] + bv, a[2] + bv, a[3] + bv);
            *(int2*)&((short*)out)[di] = pk;
        }
    }
}

// ---------------- MFMA flash attention v5: 4-way d-split, 1024 threads ----------------
// grid (8 n, 21 qtile, 8 head) — XCD-local per batch.
__global__ __launch_bounds__(1024) void k_attn(const bf16* __restrict__ Qg,
                                               const bf16* __restrict__ Kg,
                                               const bf16* __restrict__ Vcf,
                                               bf16* __restrict__ A) {
    __shared__ __align__(16) short Pl[16][16][72];   // [wave][q][d]
    __shared__ float Ocomb[3][4][16][17];            // [slot][qw][c][q]
    __shared__ float Lcomb[3][4][16];                // [slot][qw][q]

    const int tid = threadIdx.x;
    const int w = tid >> 6, lane = tid & 63;
    const int quad = lane >> 4, l16 = lane & 15;
    const int qw = w & 3, dq = w >> 2;
    const int n = blockIdx.x;
    const int qb = blockIdx.y * 64;
    const int head = blockIdx.z;
    const short* Qh = (const short*)Qg + ((size_t)(n * 8 + head)) * HW * 16;
    const short* Kh = (const short*)Kg + ((size_t)(n * 8 + head)) * HW * 16;
    const short* Vh = (const short*)Vcf + ((size_t)n * CH + head * 16) * HW;

    frag8 zf = {0, 0, 0, 0, 0, 0, 0, 0};
    frag8 qf = zf;
    const int qtok = qb + qw * 16 + l16;
    if (quad < 2 && qtok < HW)
        qf = *(const frag8*)&Qh[(size_t)qtok * 16 + quad * 8];

    f32x4 Oacc = {0.f, 0.f, 0.f, 0.f};   // O^T: lane holds O[c=quad*4+r][q=l16]
    float lsum = 0.0f;
    short* plrow = &Pl[w][l16][0];

    const int cstart = dq ? (1 + 5 * dq) : 0;   // {0,6,11,16}
    const int cend   = 6 + 5 * dq;              // {6,11,16,21}
    for (int ci = cstart; ci < cend; ++ci) {
        int d0 = ci * 64;
        bool last = (ci == 20);                  // tail: 16 valid d
        f32x4 ST[4];
        #pragma unroll
        for (int t = 0; t < 4; ++t) {
            frag8 kf = zf;
            if (quad < 2)
                kf = *(const frag8*)&Kh[(size_t)(d0 + t * 16 + l16) * 16 + quad * 8];
            f32x4 zacc = {0.f, 0.f, 0.f, 0.f};
            ST[t] = __builtin_amdgcn_mfma_f32_16x16x32_bf16(kf, qf, zacc, 0, 0, 0);
        }
        #pragma unroll
        for (int t = 0; t < 4; ++t) {
            float pf0 = __expf(ST[t][0]);
            float pf1 = __expf(ST[t][1]);
            float pf2 = __expf(ST[t][2]);
            float pf3 = __expf(ST[t][3]);
            if (last) {
                int dg = d0 + t * 16 + quad * 4;
                if (dg + 0 >= HW) pf0 = 0.0f;
                if (dg + 1 >= HW) pf1 = 0.0f;
                if (dg + 2 >= HW) pf2 = 0.0f;
                if (dg + 3 >= HW) pf3 = 0.0f;
            }
            lsum += (pf0 + pf1) + (pf2 + pf3);
            *(int2*)&plrow[t * 16 + quad * 4] = pack4(pf0, pf1, pf2, pf3);
        }
        #pragma unroll
        for (int s = 0; s < 2; ++s) {
            frag8 vf = *(const frag8*)&Vh[(size_t)l16 * HW + d0 + s * 32 + quad * 8];
            frag8 pf = *(const frag8*)&plrow[s * 32 + quad * 8];
            Oacc = __builtin_amdgcn_mfma_f32_16x16x32_bf16(vf, pf, Oacc, 0, 0, 0);
        }
    }

    lsum += __shfl_xor(lsum, 16);
    lsum += __shfl_xor(lsum, 32);

    if (dq > 0) {
        int slot = dq - 1;
        #pragma unroll
        for (int r = 0; r < 4; ++r)
            Ocomb[slot][qw][quad * 4 + r][l16] = Oacc[r];
        if (quad == 0) Lcomb[slot][qw][l16] = lsum;
    }
    __syncthreads();
    if (dq == 0) {
        #pragma unroll
        for (int s = 0; s < 3; ++s) {
            #pragma unroll
            for (int r = 0; r < 4; ++r)
                Oacc[r] += Ocomb[s][qw][quad * 4 + r][l16];
            lsum += Lcomb[s][qw][l16];
        }
        if (qtok < HW) {
            float inv = frcp(lsum);
            int2 pk = pack4(Oacc[0] * inv, Oacc[1] * inv, Oacc[2] * inv, Oacc[3] * inv);
            short* An = (short*)A + (size_t)n * HW * CH;
            *(int2*)&An[(size_t)qtok * CH + head * 16 + quad * 4] = pk;
        }
    }
}

extern "C" void kernel_launch(void* const* d_in, const int* in_sizes, int n_in,
                              void* d_out, int out_size, void* d_ws, size_t ws_size,
                              hipStream_t stream) {
    char* ws = (char*)d_ws;
    bf16*  Wst  = (bf16*)(ws + 256);          // 327680 bf16
    float* Bst  = (float*)(ws + 655616);      // 768 f32
    bf16*  XT   = (bf16*)(ws + 1048576);      // channel-last [n][1296][128]
    bf16*  Zb   = XT + TT;
    bf16*  Qb   = Zb + TT;                    // head-grouped [n][8][1296][16]
    bf16*  Kb   = Qb + TT;
    bf16*  Vb   = Kb + TT;                    // channel-first [n][128][1296]
    bf16*  Ab   = Vb + TT;
    bf16*  Hb   = Ab + TT;                    // ~19.6 MB total

    k_prep<<<1284, 256, 0, stream>>>(d_in[1], d_in[3], d_in[5], d_in[6], d_in[7],
                                     d_in[8], d_in[12], d_in[14], d_in[16],
                                     d_in[2], d_in[4], d_in[9], d_in[13], d_in[15], d_in[17],
                                     Wst, Bst);
    // n on blockIdx.x (gridDim.x == 8): linear wg id % 8 == n -> per-batch XCD locality
    k_inm<<<dim3(8, 41, 4), 256, 0, stream>>>(d_in[0], d_in[1], Wst, Bst, XT);
    k_mm<0><<<dim3(8, 21, 4), 256, 0, stream>>>(XT, nullptr, Wst + 16384, Bst + 128,
                                                Zb, nullptr, nullptr);
    k_mm<1><<<dim3(8, 21, 12), 256, 0, stream>>>(Zb, nullptr, Wst + 163840, nullptr,
                                                 Qb, Kb, Vb);
    k_attn<<<dim3(8, 21, 8), 1024, 0, stream>>>(Qb, Kb, Vb, Ab);
    k_mm<2><<<dim3(8, 21, 4), 256, 0, stream>>>(Zb, Ab, Wst + 212992, Bst + 256,
                                                Hb, nullptr, nullptr);
    k_outm<<<dim3(8, 41, 2), 256, 0, stream>>>(Hb, Wst + 311296, Bst + 640, d_out, d_in[1]);
}